// Round 14
// baseline (177.097 us; speedup 1.0000x reference)
//
#include <hip/hip_runtime.h>

typedef unsigned short u16;
typedef unsigned int u32;
typedef __attribute__((ext_vector_type(8))) short s16x8;
typedef __attribute__((ext_vector_type(2))) float f32x2;
typedef __attribute__((ext_vector_type(4))) float f32x4;
typedef __attribute__((ext_vector_type(16))) float f32x16;
typedef __attribute__((ext_vector_type(2))) u32 u32x2;
typedef __attribute__((ext_vector_type(4))) u32 u32x4;

#define MB (1ull << 20)
#define K1SCALE 0.18033688f  // 0.125 * log2(e)

__device__ __forceinline__ u16 f2bf(float f) {
  u32 u = __float_as_uint(f);
  u32 r = (u + 0x7fffu + ((u >> 16) & 1u)) >> 16;
  return (u16)r;
}

__device__ __forceinline__ u32 cvtpk(float lo, float hi) {
  u32 r;
  asm("v_cvt_pk_bf16_f32 %0, %1, %2" : "=v"(r) : "v"(lo), "v"(hi));
  return r;
}

__device__ __forceinline__ f32x2 pk_add(f32x2 a, f32x2 b) {
  f32x2 d;
  asm("v_pk_add_f32 %0, %1, %2" : "=v"(d) : "v"(a), "v"(b));
  return d;
}

__device__ __forceinline__ void gload16(const u16* g, u16* l) {
  __builtin_amdgcn_global_load_lds((const __attribute__((address_space(1))) void*)g,
                                   (__attribute__((address_space(3))) void*)l, 16, 0, 0);
}

// ---------------- prep: posenc (blocks 0..8191) + weight transpose/cast (8192..11269) ----
__global__ __launch_bounds__(256) void k_prep(const float* __restrict__ x,
                                              float* __restrict__ xf, u16* __restrict__ xb,
                                              const float* __restrict__ Wq, const float* __restrict__ Wk,
                                              const float* __restrict__ Wv, const float* __restrict__ Wo,
                                              const float* __restrict__ Wff1, const float* __restrict__ Wff2,
                                              const float* __restrict__ bq, const float* __restrict__ bk,
                                              const float* __restrict__ bv,
                                              u16* __restrict__ WqkvT, u16* __restrict__ WoT,
                                              u16* __restrict__ Wff1T, u16* __restrict__ Wff2T,
                                              float* __restrict__ bqkv) {
  __shared__ float tile[32][33];
  int bid = blockIdx.x;
  if (bid < 8192) {  // positional encoding, one thread = one (sin,cos) pair
    int idx = bid * 256 + threadIdx.x;
    int i2 = idx & 255;
    int srow = (idx >> 8) & 2047;
    float div = __expf((float)i2 * -0.03597789207803196f);
    float ang = (float)srow * div;
    f32x2 xv = *(const f32x2*)&x[(size_t)idx * 2];
    float v0 = xv[0] + __sinf(ang);
    float v1 = xv[1] + __cosf(ang);
    *(f32x2*)&xf[(size_t)idx * 2] = (f32x2){v0, v1};
    *(u32*)&xb[(size_t)idx * 2] = cvtpk(v0, v1);
    return;
  }
  int id = bid - 8192;
  if (id >= 3072) {  // bias concat (+ fold softmax scale into bq)
    int j = (id - 3072) * 256 + threadIdx.x;  // < 1536
    float v = (j < 512) ? bq[j] * K1SCALE : ((j < 1024) ? bk[j - 512] : bv[j - 1024]);
    bqkv[j] = v;
    return;
  }
  const float* W;
  u16* Wt;
  int K, N, k0, n0;
  float sc = 1.0f;
  if (id < 1024) {  // four 512x512 mats
    int mi = id >> 8, t = id & 255;
    K = 512; N = 512;
    k0 = (t & 15) * 32;
    n0 = (t >> 4) * 32;
    if (mi == 0) { W = Wq; Wt = WqkvT; sc = K1SCALE; }
    else if (mi == 1) { W = Wk; Wt = WqkvT + 512 * 512; }
    else if (mi == 2) { W = Wv; Wt = WqkvT + 2 * 512 * 512; }
    else { W = Wo; Wt = WoT; }
  } else if (id < 2048) {  // Wff1: [512][2048]
    int t = id - 1024;
    K = 512; N = 2048;
    k0 = (t & 15) * 32;
    n0 = (t >> 4) * 32;
    W = Wff1; Wt = Wff1T;
  } else {  // Wff2: [2048][512]
    int t = id - 2048;
    K = 2048; N = 512;
    k0 = (t >> 4) * 32;
    n0 = (t & 15) * 32;
    W = Wff2; Wt = Wff2T;
  }
  int tx = threadIdx.x & 31, ty = threadIdx.x >> 5;
  #pragma unroll
  for (int i = 0; i < 32; i += 8)
    tile[ty + i][tx] = W[(size_t)(k0 + ty + i) * N + n0 + tx];
  __syncthreads();
  #pragma unroll
  for (int i = 0; i < 32; i += 8)
    Wt[(size_t)(n0 + ty + i) * K + k0 + tx] = f2bf(tile[tx][ty + i] * sc);
}

// ---------------- pipelined GEMM: 256x128 tile, 8 waves, 3-buffer LDS, counted vmcnt ----
// XCD-swizzled block mapping: consecutive row-tiles land on the same XCD's L2.
template <int NK, bool RELU, bool QKV, bool F32OUT>
__global__ __launch_bounds__(512, 2) void k_gemm3(const u16* __restrict__ A, const u16* __restrict__ Bt,
                                                  const float* __restrict__ bias, u16* __restrict__ Cb,
                                                  u16* __restrict__ vTout,
                                                  float* __restrict__ Cf0, float* __restrict__ Cf1,
                                                  int N, int lda) {
  constexpr int K = NK * 64;
  __shared__ u16 lA[3][256 * 64];  // 96 KB
  __shared__ u16 lB[3][128 * 64];  // 48 KB
  int t = threadIdx.x;
  int lane = t & 63;
  int w = t >> 6;
  int wr = w >> 1, wc = w & 1;
  int g = lane >> 4, c = lane & 15;
  // XCD swizzle (nwg % 8 == 0 for all our grids)
  int nwg = gridDim.x * gridDim.y;
  int fid = blockIdx.y * gridDim.x + blockIdx.x;
  int wid = (fid & 7) * (nwg >> 3) + (fid >> 3);
  int bx = wid / gridDim.y;
  int by = wid % gridDim.y;
  size_t tm = (size_t)bx * 256;
  size_t tn = (size_t)by * 128;
  A += (size_t)blockIdx.z * K;
  Bt += (size_t)blockIdx.z * K;

  auto stg = [&](int buf, int kt, int half) {
    int k0 = kt * 64;
    #pragma unroll
    for (int i = 0; i < 2; i++) {
      int ch = t + (half * 2 + i) * 512;
      int row = ch >> 3;
      int koff = ((ch ^ row) & 7) << 3;
      gload16(A + (tm + row) * lda + k0 + koff, &lA[buf][ch * 8]);
    }
    int ch = t + half * 512;
    int row = ch >> 3;
    int koff = ((ch ^ row) & 7) << 3;
    gload16(Bt + (tn + row) * lda + k0 + koff, &lB[buf][ch * 8]);
  };

  f32x4 acc[4][4];
  #pragma unroll
  for (int i = 0; i < 4; i++)
    #pragma unroll
    for (int j = 0; j < 4; j++) acc[i][j] = (f32x4){0.f, 0.f, 0.f, 0.f};

  stg(0, 0, 0); stg(0, 0, 1);
  stg(1, 1, 0); stg(1, 1, 1);
  asm volatile("s_waitcnt vmcnt(6)" ::: "memory");
  __builtin_amdgcn_s_barrier();
  __builtin_amdgcn_sched_barrier(0);

  #pragma unroll
  for (int kt = 0; kt < NK; kt++) {
    const int buf = kt % 3;
    const int nb = (kt + 2) % 3;
    s16x8 bfr[4][2], afr[2][2];
    #pragma unroll
    for (int nr = 0; nr < 4; nr++)
      #pragma unroll
      for (int ks = 0; ks < 2; ks++)
        bfr[nr][ks] = *(const s16x8*)&lB[buf][(wc * 64 + nr * 16 + c) * 64 + (((g + 4 * ks) ^ (c & 7)) << 3)];
    #pragma unroll
    for (int mr = 0; mr < 2; mr++)
      #pragma unroll
      for (int ks = 0; ks < 2; ks++)
        afr[mr][ks] = *(const s16x8*)&lA[buf][(wr * 64 + mr * 16 + c) * 64 + (((g + 4 * ks) ^ (c & 7)) << 3)];
    if (kt + 2 < NK) stg(nb, kt + 2, 0);
    __builtin_amdgcn_s_barrier();
    __builtin_amdgcn_sched_barrier(0);
    __builtin_amdgcn_s_setprio(1);
    #pragma unroll
    for (int mr = 0; mr < 2; mr++)
      #pragma unroll
      for (int nr = 0; nr < 4; nr++)
        #pragma unroll
        for (int ks = 0; ks < 2; ks++)
          acc[mr][nr] = __builtin_amdgcn_mfma_f32_16x16x32_bf16(afr[mr][ks], bfr[nr][ks], acc[mr][nr], 0, 0, 0);
    __builtin_amdgcn_s_setprio(0);
    __builtin_amdgcn_s_barrier();
    __builtin_amdgcn_sched_barrier(0);
    #pragma unroll
    for (int mr = 0; mr < 2; mr++)
      #pragma unroll
      for (int ks = 0; ks < 2; ks++)
        afr[mr][ks] = *(const s16x8*)&lA[buf][(wr * 64 + (mr + 2) * 16 + c) * 64 + (((g + 4 * ks) ^ (c & 7)) << 3)];
    if (kt + 2 < NK) stg(nb, kt + 2, 1);
    __builtin_amdgcn_s_barrier();
    __builtin_amdgcn_sched_barrier(0);
    __builtin_amdgcn_s_setprio(1);
    #pragma unroll
    for (int mr = 0; mr < 2; mr++)
      #pragma unroll
      for (int nr = 0; nr < 4; nr++)
        #pragma unroll
        for (int ks = 0; ks < 2; ks++)
          acc[mr + 2][nr] = __builtin_amdgcn_mfma_f32_16x16x32_bf16(afr[mr][ks], bfr[nr][ks], acc[mr + 2][nr], 0, 0, 0);
    __builtin_amdgcn_s_setprio(0);
    if (kt < NK - 1) {
      if (kt + 2 < NK)
        asm volatile("s_waitcnt vmcnt(6)" ::: "memory");
      else
        asm volatile("s_waitcnt vmcnt(0)" ::: "memory");
      __builtin_amdgcn_s_barrier();
      __builtin_amdgcn_sched_barrier(0);
    }
  }

  // ---- epilogue ----
  if (QKV && tn >= 1024) {
    #pragma unroll
    for (int mr = 0; mr < 4; mr++) {
      int row0 = (int)tm + wr * 64 + mr * 16 + g * 4;
      int b = row0 >> 11, s0 = row0 & 2047;
      #pragma unroll
      for (int nr = 0; nr < 4; nr++) {
        int colr = (int)(tn - 1024) + wc * 64 + nr * 16 + c;
        int h = colr >> 6, d = colr & 63;
        float bv = bias[1024 + colr];
        u32 w0 = cvtpk(acc[mr][nr][0] + bv, acc[mr][nr][1] + bv);
        u32 w1 = cvtpk(acc[mr][nr][2] + bv, acc[mr][nr][3] + bv);
        u32x2 pp = {w0, w1};
        *(u32x2*)&vTout[((size_t)((b << 3) + h) * 64 + d) * 2048 + s0] = pp;
      }
    }
  } else if (F32OUT) {
    float* Cf = blockIdx.z ? Cf1 : Cf0;
    bool addb = (blockIdx.z == 0);
    #pragma unroll
    for (int nr = 0; nr < 4; nr++) {
      size_t col = tn + wc * 64 + nr * 16 + c;
      float bv = addb ? bias[col] : 0.0f;
      #pragma unroll
      for (int mr = 0; mr < 4; mr++) {
        size_t row0 = tm + wr * 64 + mr * 16 + g * 4;
        #pragma unroll
        for (int r = 0; r < 4; r++) Cf[(row0 + r) * N + col] = acc[mr][nr][r] + bv;
      }
    }
  } else {
    #pragma unroll
    for (int nr = 0; nr < 4; nr++) {
      size_t col = tn + wc * 64 + nr * 16 + c;
      float bv = bias[col];
      #pragma unroll
      for (int mr = 0; mr < 4; mr++) {
        size_t row0 = tm + wr * 64 + mr * 16 + g * 4;
        #pragma unroll
        for (int r = 0; r < 4; r++) {
          float v = acc[mr][nr][r] + bv;
          if (RELU) v = fmaxf(v, 0.0f);
          Cb[(row0 + r) * N + col] = f2bf(v);
        }
      }
    }
  }
}

// ---------------- flash attention: 8 waves = 4 q-groups x 2 key-halves, dbuf pipeline ----
// (Round-9-proven structure: vmcnt(0)+barrier per step.) XCD-swizzled 1D grid: each XCD
// owns 4 consecutive bh -> its 2MB K/V slab is L2-resident.
// No online max: P = exp2(s) directly (s bounded); in-block merge of key-halves (l only).
union F16U {
  f32x16 v;
  f32x2 p[8];
};

__global__ __launch_bounds__(512, 4) void k_attn(const u16* __restrict__ qkv,
                                                 const u16* __restrict__ vT,
                                                 u16* __restrict__ ctx) {
  __shared__ u16 lds[8][4096];  // [(stream*2+buf)*2+kv][4096]; 64 KB
  int t = threadIdx.x;
  int w = t >> 6, lane = t & 63;
  int qg = w >> 1, kh = w & 1;
  int ql = lane & 31, hi = lane >> 5;
  int bid = blockIdx.x;
  int wid = (bid & 7) * 64 + (bid >> 3);  // XCD swizzle over 512 blocks
  int bx = wid & 15;
  int bh = wid >> 4;
  int b = bh >> 3, h = bh & 7;
  int q0 = bx * 128 + qg * 32;
  int r7 = ql & 7;

  int sh = t >> 8;
  int th = t & 255;
  const u16* kbaseg = qkv + (size_t)(b * 2048 + sh * 1024) * 1536 + 512 + h * 64;
  const u16* vbaseg = vT + (size_t)(bh * 64) * 2048 + sh * 1024;

  auto stage = [&](int buf, int step) {
    int t0 = step * 64;
    #pragma unroll
    for (int i = 0; i < 2; i++) {
      int ch = th + i * 256;
      int row = ch >> 3;
      int off = ((ch ^ row) & 7) << 3;
      gload16(kbaseg + (size_t)(t0 + row) * 1536 + off, &lds[(sh * 2 + buf) * 2][ch * 8]);
      gload16(vbaseg + (size_t)row * 2048 + t0 + off, &lds[(sh * 2 + buf) * 2 + 1][ch * 8]);
    }
  };

  const u16* qbase = qkv + (size_t)(b * 2048 + q0 + ql) * 1536 + h * 64 + hi * 8;
  s16x8 qf[4];
  #pragma unroll
  for (int ks = 0; ks < 4; ks++) qf[ks] = *(const s16x8*)(qbase + ks * 16);

  float l = 0.f;
  F16U O0, O1;
  #pragma unroll
  for (int i = 0; i < 16; i++) { O0.v[i] = 0.f; O1.v[i] = 0.f; }

  stage(0, 0);

  for (int step = 0; step < 16; ++step) {
    int buf = step & 1;
    asm volatile("s_waitcnt vmcnt(0)" ::: "memory");
    __builtin_amdgcn_s_barrier();
    __builtin_amdgcn_sched_barrier(0);
    if (step < 15) stage(buf ^ 1, step + 1);

    const u16* lK = lds[(kh * 2 + buf) * 2];
    const u16* lV = lds[(kh * 2 + buf) * 2 + 1];

    F16U S0, S1;
    #pragma unroll
    for (int i = 0; i < 16; i++) { S0.v[i] = 0.f; S1.v[i] = 0.f; }
    #pragma unroll
    for (int ks = 0; ks < 4; ks++) {
      int so = ((ks * 2 + hi) ^ r7) << 3;
      s16x8 kf0 = *(const s16x8*)&lK[ql * 64 + so];
      s16x8 kf1 = *(const s16x8*)&lK[(32 + ql) * 64 + so];
      S0.v = __builtin_amdgcn_mfma_f32_32x32x16_bf16(kf0, qf[ks], S0.v, 0, 0, 0);
      S1.v = __builtin_amdgcn_mfma_f32_32x32x16_bf16(kf1, qf[ks], S1.v, 0, 0, 0);
    }

    // P = exp2(s), no max subtraction (softmax shift-invariant; s bounded)
    #pragma unroll
    for (int i = 0; i < 16; i++) {
      S0.v[i] = __builtin_amdgcn_exp2f(S0.v[i]);
      S1.v[i] = __builtin_amdgcn_exp2f(S1.v[i]);
    }
    f32x2 c0 = pk_add(S0.p[0], S0.p[1]);
    f32x2 c1 = pk_add(S0.p[2], S0.p[3]);
    f32x2 c2 = pk_add(S0.p[4], S0.p[5]);
    f32x2 c3 = pk_add(S0.p[6], S0.p[7]);
    f32x2 d0 = pk_add(S1.p[0], S1.p[1]);
    f32x2 d1 = pk_add(S1.p[2], S1.p[3]);
    f32x2 d2 = pk_add(S1.p[4], S1.p[5]);
    f32x2 d3 = pk_add(S1.p[6], S1.p[7]);
    c0 = pk_add(c0, c1);
    c2 = pk_add(c2, c3);
    d0 = pk_add(d0, d1);
    d2 = pk_add(d2, d3);
    c0 = pk_add(c0, c2);
    d0 = pk_add(d0, d2);
    c0 = pk_add(c0, d0);
    float pssum = c0[0] + c0[1];
    pssum += __shfl_xor(pssum, 32, 64);
    l += pssum;

    auto pv = [&](const f32x16& sv, int kb) {
      u32 a0w = cvtpk(sv[0], sv[1]), a1w = cvtpk(sv[2], sv[3]);
      u32 a2w = cvtpk(sv[4], sv[5]), a3w = cvtpk(sv[6], sv[7]);
      u32 b0w = cvtpk(sv[8], sv[9]), b1w = cvtpk(sv[10], sv[11]);
      u32 b2w = cvtpk(sv[12], sv[13]), b3w = cvtpk(sv[14], sv[15]);
      asm("v_permlane32_swap_b32 %0, %1" : "+v"(a0w), "+v"(a2w));
      asm("v_permlane32_swap_b32 %0, %1" : "+v"(a1w), "+v"(a3w));
      asm("v_permlane32_swap_b32 %0, %1" : "+v"(b0w), "+v"(b2w));
      asm("v_permlane32_swap_b32 %0, %1" : "+v"(b1w), "+v"(b3w));
      u32x4 w0v = {a0w, a1w, a2w, a3w};
      u32x4 w1v = {b0w, b1w, b2w, b3w};
      s16x8 pf0 = __builtin_bit_cast(s16x8, w0v);
      s16x8 pf1 = __builtin_bit_cast(s16x8, w1v);
      int base0 = ((kb * 4 + hi) ^ r7) << 3;
      int base1 = ((kb * 4 + 2 + hi) ^ r7) << 3;
      s16x8 vf00 = *(const s16x8*)&lV[ql * 64 + base0];
      s16x8 vf01 = *(const s16x8*)&lV[ql * 64 + base1];
      s16x8 vf10 = *(const s16x8*)&lV[(32 + ql) * 64 + base0];
      s16x8 vf11 = *(const s16x8*)&lV[(32 + ql) * 64 + base1];
      O0.v = __builtin_amdgcn_mfma_f32_32x32x16_bf16(vf00, pf0, O0.v, 0, 0, 0);
      O0.v = __builtin_amdgcn_mfma_f32_32x32x16_bf16(vf01, pf1, O0.v, 0, 0, 0);
      O1.v = __builtin_amdgcn_mfma_f32_32x32x16_bf16(vf10, pf0, O1.v, 0, 0, 0);
      O1.v = __builtin_amdgcn_mfma_f32_32x32x16_bf16(vf11, pf1, O1.v, 0, 0, 0);
    };
    pv(S0.v, 0);
    pv(S1.v, 1);
  }

  // ---- in-block merge of the two key-halves (l only) ----
  asm volatile("s_waitcnt lgkmcnt(0)" ::: "memory");
  __builtin_amdgcn_s_barrier();
  float* mrg = (float*)&lds[0][0];  // [qg*64+lane][34] floats
  float* p = mrg + (size_t)(qg * 64 + lane) * 34;
  if (kh == 1) {
    p[0] = l;
    #pragma unroll
    for (int i = 0; i < 16; i++) {
      p[1 + i] = O0.v[i];
      p[17 + i] = O1.v[i];
    }
  }
  asm volatile("s_waitcnt lgkmcnt(0)" ::: "memory");
  __builtin_amdgcn_s_barrier();
  if (kh == 0) {
    float inv = 1.0f / (l + p[0]);
    size_t obase = (size_t)(b * 2048 + q0 + ql) * 512 + h * 64;
    #pragma unroll
    for (int k = 0; k < 4; k++) {
      float v0 = (O0.v[4 * k] + p[1 + 4 * k]) * inv;
      float v1 = (O0.v[4 * k + 1] + p[1 + 4 * k + 1]) * inv;
      float v2 = (O0.v[4 * k + 2] + p[1 + 4 * k + 2]) * inv;
      float v3 = (O0.v[4 * k + 3] + p[1 + 4 * k + 3]) * inv;
      u32x2 p0 = {cvtpk(v0, v1), cvtpk(v2, v3)};
      *(u32x2*)&ctx[obase + 8 * k + 4 * hi] = p0;
      float u0 = (O1.v[4 * k] + p[17 + 4 * k]) * inv;
      float u1 = (O1.v[4 * k + 1] + p[17 + 4 * k + 1]) * inv;
      float u2 = (O1.v[4 * k + 2] + p[17 + 4 * k + 2]) * inv;
      float u3 = (O1.v[4 * k + 3] + p[17 + 4 * k + 3]) * inv;
      u32x2 p1 = {cvtpk(u0, u1), cvtpk(u2, u3)};
      *(u32x2*)&ctx[obase + 32 + 8 * k + 4 * hi] = p1;
    }
  }
}

// ---------------- 3-way residual add + LayerNorm, optional bf16 copy ----------------
template <bool WB>
__global__ __launch_bounds__(256) void k_addln3(const float* __restrict__ A, const float* __restrict__ B1,
                                                const float* __restrict__ B2,
                                                const float* __restrict__ G, const float* __restrict__ Bb,
                                                float* __restrict__ Of, u16* __restrict__ Ob) {
  int row = blockIdx.x;
  int t = threadIdx.x;
  size_t base = (size_t)row * 512 + 2 * t;
  f32x2 av = *(const f32x2*)&A[base];
  f32x2 b1v = *(const f32x2*)&B1[base];
  f32x2 b2v = *(const f32x2*)&B2[base];
  float x0 = av[0] + b1v[0] + b2v[0];
  float x1 = av[1] + b1v[1] + b2v[1];
  float s = x0 + x1;
  #pragma unroll
  for (int d = 1; d < 64; d <<= 1) s += __shfl_xor(s, d, 64);
  __shared__ float red[8];
  int w = t >> 6, lane = t & 63;
  if (lane == 0) red[w] = s;
  __syncthreads();
  float mu = (red[0] + red[1] + red[2] + red[3]) * (1.0f / 512.0f);
  float d0 = x0 - mu, d1 = x1 - mu;
  float vs = d0 * d0 + d1 * d1;
  #pragma unroll
  for (int d = 1; d < 64; d <<= 1) vs += __shfl_xor(vs, d, 64);
  if (lane == 0) red[4 + w] = vs;
  __syncthreads();
  float var = (red[4] + red[5] + red[6] + red[7]) * (1.0f / 512.0f);
  float rs = rsqrtf(var + 1e-5f);
  f32x2 gg = *(const f32x2*)&G[2 * t];
  f32x2 bb = *(const f32x2*)&Bb[2 * t];
  float o0 = d0 * rs * gg[0] + bb[0];
  float o1 = d1 * rs * gg[1] + bb[1];
  *(f32x2*)&Of[base] = (f32x2){o0, o1};
  if (WB) *(u32*)&Ob[base] = cvtpk(o0, o1);
}

// ---------------- launch ----------------
extern "C" void kernel_launch(void* const* d_in, const int* in_sizes, int n_in,
                              void* d_out, int out_size, void* d_ws, size_t ws_size,
                              hipStream_t stream) {
  const float* x = (const float*)d_in[0];
  const float* Wq = (const float*)d_in[1];
  const float* bq = (const float*)d_in[2];
  const float* Wk = (const float*)d_in[3];
  const float* bk = (const float*)d_in[4];
  const float* Wv = (const float*)d_in[5];
  const float* bv = (const float*)d_in[6];
  const float* Wo = (const float*)d_in[7];
  const float* bo = (const float*)d_in[8];
  const float* g1 = (const float*)d_in[9];
  const float* b1 = (const float*)d_in[10];
  const float* Wff1 = (const float*)d_in[11];
  const float* bff1 = (const float*)d_in[12];
  const float* Wff2 = (const float*)d_in[13];
  const float* bff2 = (const float*)d_in[14];
  const float* g2 = (const float*)d_in[15];
  const float* b2 = (const float*)d_in[16];

  char* ws = (char*)d_ws;
  float* xpe_f = (float*)(ws + 0);            // 16MB (dead after LN1 -> reused as ao2 for FF2)
  float* ao2 = (float*)(ws + 0);              // 16MB FF2 partial z=1
  u16* xpe_b = (u16*)(ws + 16 * MB);          // 8MB
  u16* qkv = (u16*)(ws + 24 * MB);            // 24MB  [8192][1536] (V cols unused)
  u16* vT = (u16*)(ws + 48 * MB);             // 8MB   [32][64][2048]
  u16* ctx = (u16*)(ws + 56 * MB);            // 8MB   [8192][512]
  float* ao = (float*)(ws + 64 * MB);         // 16MB  O-proj/FF2 partial z=0
  float* hf = (float*)(ws + 80 * MB);         // 16MB  O-proj partial z=1, then LN1 output
  u16* hb = (u16*)(ws + 96 * MB);             // 8MB
  u16* ff1 = (u16*)(ws + 24 * MB);            // 32MB, aliases qkv+vT (dead by then)
  u16* WqkvT = (u16*)(ws + 104 * MB);         // 1.5MB [1536][512]
  u16* WoT = (u16*)(ws + 106 * MB);           // 0.5MB
  u16* Wff1T = (u16*)(ws + 107 * MB);         // 2MB [2048][512]
  u16* Wff2T = (u16*)(ws + 109 * MB);         // 2MB [512][2048]
  float* bqkv = (float*)(ws + 111 * MB);      // 6KB
  (void)in_sizes; (void)n_in; (void)out_size; (void)ws_size;

  k_prep<<<11270, 256, 0, stream>>>(x, xpe_f, xpe_b, Wq, Wk, Wv, Wo, Wff1, Wff2,
                                    bq, bk, bv, WqkvT, WoT, Wff1T, Wff2T, bqkv);

  // fused QKV projection (V written transposed straight into vT)
  k_gemm3<8, false, true, false><<<dim3(32, 12), 512, 0, stream>>>(xpe_b, WqkvT, bqkv, qkv, vT,
                                                                   nullptr, nullptr, 1536, 512);
  k_attn<<<512, 512, 0, stream>>>(qkv, vT, ctx);
  // O projection: pipelined split-K x2 (z=0 -> ao with bias, z=1 -> hf), 256 blocks
  k_gemm3<4, false, false, true><<<dim3(32, 4, 2), 512, 0, stream>>>(ctx, WoT, bo, nullptr, nullptr,
                                                                     ao, hf, 512, 512);
  // LN1: h = LN(xpe + ao + hf) -> hf (f32) + hb (bf16)
  k_addln3<true><<<8192, 256, 0, stream>>>(xpe_f, ao, hf, g1, b1, hf, hb);
  // FFN
  k_gemm3<8, true, false, false><<<dim3(32, 16), 512, 0, stream>>>(hb, Wff1T, bff1, ff1, nullptr,
                                                                   nullptr, nullptr, 2048, 512);
  // FF2 split-K x2, pipelined, f32 partials (z=0 -> ao with bias, z=1 -> ao2)
  k_gemm3<16, false, false, true><<<dim3(32, 4, 2), 512, 0, stream>>>(ff1, Wff2T, bff2, nullptr, nullptr,
                                                                      ao, ao2, 512, 2048);
  k_addln3<false><<<8192, 256, 0, stream>>>(hf, ao, ao2, g2, b2, (float*)d_out, nullptr);
}

// Round 15
// 171.512 us; speedup vs baseline: 1.0326x; 1.0326x over previous
//
#include <hip/hip_runtime.h>

typedef unsigned short u16;
typedef unsigned int u32;
typedef __attribute__((ext_vector_type(8))) short s16x8;
typedef __attribute__((ext_vector_type(2))) float f32x2;
typedef __attribute__((ext_vector_type(4))) float f32x4;
typedef __attribute__((ext_vector_type(16))) float f32x16;
typedef __attribute__((ext_vector_type(2))) u32 u32x2;
typedef __attribute__((ext_vector_type(4))) u32 u32x4;

#define MB (1ull << 20)
#define K1SCALE 0.18033688f  // 0.125 * log2(e)

__device__ __forceinline__ u16 f2bf(float f) {
  u32 u = __float_as_uint(f);
  u32 r = (u + 0x7fffu + ((u >> 16) & 1u)) >> 16;
  return (u16)r;
}

__device__ __forceinline__ u32 cvtpk(float lo, float hi) {
  u32 r;
  asm("v_cvt_pk_bf16_f32 %0, %1, %2" : "=v"(r) : "v"(lo), "v"(hi));
  return r;
}

__device__ __forceinline__ f32x2 pk_add(f32x2 a, f32x2 b) {
  f32x2 d;
  asm("v_pk_add_f32 %0, %1, %2" : "=v"(d) : "v"(a), "v"(b));
  return d;
}

__device__ __forceinline__ void gload16(const u16* g, u16* l) {
  __builtin_amdgcn_global_load_lds((const __attribute__((address_space(1))) void*)g,
                                   (__attribute__((address_space(3))) void*)l, 16, 0, 0);
}

// ---------------- prep: posenc (blocks 0..8191) + weight transpose/cast (8192..11269) ----
__global__ __launch_bounds__(256) void k_prep(const float* __restrict__ x,
                                              float* __restrict__ xf, u16* __restrict__ xb,
                                              const float* __restrict__ Wq, const float* __restrict__ Wk,
                                              const float* __restrict__ Wv, const float* __restrict__ Wo,
                                              const float* __restrict__ Wff1, const float* __restrict__ Wff2,
                                              const float* __restrict__ bq, const float* __restrict__ bk,
                                              const float* __restrict__ bv,
                                              u16* __restrict__ WqkvT, u16* __restrict__ WoT,
                                              u16* __restrict__ Wff1T, u16* __restrict__ Wff2T,
                                              float* __restrict__ bqkv) {
  __shared__ float tile[32][33];
  int bid = blockIdx.x;
  if (bid < 8192) {  // positional encoding, one thread = one (sin,cos) pair
    int idx = bid * 256 + threadIdx.x;
    int i2 = idx & 255;
    int srow = (idx >> 8) & 2047;
    float div = __expf((float)i2 * -0.03597789207803196f);
    float ang = (float)srow * div;
    f32x2 xv = *(const f32x2*)&x[(size_t)idx * 2];
    float v0 = xv[0] + __sinf(ang);
    float v1 = xv[1] + __cosf(ang);
    *(f32x2*)&xf[(size_t)idx * 2] = (f32x2){v0, v1};
    *(u32*)&xb[(size_t)idx * 2] = cvtpk(v0, v1);
    return;
  }
  int id = bid - 8192;
  if (id >= 3072) {  // bias concat (+ fold softmax scale into bq)
    int j = (id - 3072) * 256 + threadIdx.x;  // < 1536
    float v = (j < 512) ? bq[j] * K1SCALE : ((j < 1024) ? bk[j - 512] : bv[j - 1024]);
    bqkv[j] = v;
    return;
  }
  const float* W;
  u16* Wt;
  int K, N, k0, n0;
  float sc = 1.0f;
  if (id < 1024) {  // four 512x512 mats
    int mi = id >> 8, t = id & 255;
    K = 512; N = 512;
    k0 = (t & 15) * 32;
    n0 = (t >> 4) * 32;
    if (mi == 0) { W = Wq; Wt = WqkvT; sc = K1SCALE; }
    else if (mi == 1) { W = Wk; Wt = WqkvT + 512 * 512; }
    else if (mi == 2) { W = Wv; Wt = WqkvT + 2 * 512 * 512; }
    else { W = Wo; Wt = WoT; }
  } else if (id < 2048) {  // Wff1: [512][2048]
    int t = id - 1024;
    K = 512; N = 2048;
    k0 = (t & 15) * 32;
    n0 = (t >> 4) * 32;
    W = Wff1; Wt = Wff1T;
  } else {  // Wff2: [2048][512]
    int t = id - 2048;
    K = 2048; N = 512;
    k0 = (t >> 4) * 32;
    n0 = (t & 15) * 32;
    W = Wff2; Wt = Wff2T;
  }
  int tx = threadIdx.x & 31, ty = threadIdx.x >> 5;
  #pragma unroll
  for (int i = 0; i < 32; i += 8)
    tile[ty + i][tx] = W[(size_t)(k0 + ty + i) * N + n0 + tx];
  __syncthreads();
  #pragma unroll
  for (int i = 0; i < 32; i += 8)
    Wt[(size_t)(n0 + ty + i) * K + k0 + tx] = f2bf(tile[tx][ty + i] * sc);
}

// ---------------- pipelined GEMM: 256x128 tile, 8 waves, 3-buffer LDS, counted vmcnt ----
// XCD-swizzled block mapping: consecutive row-tiles land on the same XCD's L2.
template <int NK, bool RELU, bool QKV, bool F32OUT>
__global__ __launch_bounds__(512, 2) void k_gemm3(const u16* __restrict__ A, const u16* __restrict__ Bt,
                                                  const float* __restrict__ bias, u16* __restrict__ Cb,
                                                  u16* __restrict__ vTout,
                                                  float* __restrict__ Cf0, float* __restrict__ Cf1,
                                                  int N, int lda) {
  constexpr int K = NK * 64;
  __shared__ u16 lA[3][256 * 64];  // 96 KB
  __shared__ u16 lB[3][128 * 64];  // 48 KB
  int t = threadIdx.x;
  int lane = t & 63;
  int w = t >> 6;
  int wr = w >> 1, wc = w & 1;
  int g = lane >> 4, c = lane & 15;
  // XCD swizzle (nwg % 8 == 0 for all our grids)
  int nwg = gridDim.x * gridDim.y;
  int fid = blockIdx.y * gridDim.x + blockIdx.x;
  int wid = (fid & 7) * (nwg >> 3) + (fid >> 3);
  int bx = wid / gridDim.y;
  int by = wid % gridDim.y;
  size_t tm = (size_t)bx * 256;
  size_t tn = (size_t)by * 128;
  A += (size_t)blockIdx.z * K;
  Bt += (size_t)blockIdx.z * K;

  auto stg = [&](int buf, int kt, int half) {
    int k0 = kt * 64;
    #pragma unroll
    for (int i = 0; i < 2; i++) {
      int ch = t + (half * 2 + i) * 512;
      int row = ch >> 3;
      int koff = ((ch ^ row) & 7) << 3;
      gload16(A + (tm + row) * lda + k0 + koff, &lA[buf][ch * 8]);
    }
    int ch = t + half * 512;
    int row = ch >> 3;
    int koff = ((ch ^ row) & 7) << 3;
    gload16(Bt + (tn + row) * lda + k0 + koff, &lB[buf][ch * 8]);
  };

  f32x4 acc[4][4];
  #pragma unroll
  for (int i = 0; i < 4; i++)
    #pragma unroll
    for (int j = 0; j < 4; j++) acc[i][j] = (f32x4){0.f, 0.f, 0.f, 0.f};

  stg(0, 0, 0); stg(0, 0, 1);
  stg(1, 1, 0); stg(1, 1, 1);
  asm volatile("s_waitcnt vmcnt(6)" ::: "memory");
  __builtin_amdgcn_s_barrier();
  __builtin_amdgcn_sched_barrier(0);

  #pragma unroll
  for (int kt = 0; kt < NK; kt++) {
    const int buf = kt % 3;
    const int nb = (kt + 2) % 3;
    s16x8 bfr[4][2], afr[2][2];
    #pragma unroll
    for (int nr = 0; nr < 4; nr++)
      #pragma unroll
      for (int ks = 0; ks < 2; ks++)
        bfr[nr][ks] = *(const s16x8*)&lB[buf][(wc * 64 + nr * 16 + c) * 64 + (((g + 4 * ks) ^ (c & 7)) << 3)];
    #pragma unroll
    for (int mr = 0; mr < 2; mr++)
      #pragma unroll
      for (int ks = 0; ks < 2; ks++)
        afr[mr][ks] = *(const s16x8*)&lA[buf][(wr * 64 + mr * 16 + c) * 64 + (((g + 4 * ks) ^ (c & 7)) << 3)];
    if (kt + 2 < NK) stg(nb, kt + 2, 0);
    __builtin_amdgcn_s_barrier();
    __builtin_amdgcn_sched_barrier(0);
    __builtin_amdgcn_s_setprio(1);
    #pragma unroll
    for (int mr = 0; mr < 2; mr++)
      #pragma unroll
      for (int nr = 0; nr < 4; nr++)
        #pragma unroll
        for (int ks = 0; ks < 2; ks++)
          acc[mr][nr] = __builtin_amdgcn_mfma_f32_16x16x32_bf16(afr[mr][ks], bfr[nr][ks], acc[mr][nr], 0, 0, 0);
    __builtin_amdgcn_s_setprio(0);
    __builtin_amdgcn_s_barrier();
    __builtin_amdgcn_sched_barrier(0);
    #pragma unroll
    for (int mr = 0; mr < 2; mr++)
      #pragma unroll
      for (int ks = 0; ks < 2; ks++)
        afr[mr][ks] = *(const s16x8*)&lA[buf][(wr * 64 + (mr + 2) * 16 + c) * 64 + (((g + 4 * ks) ^ (c & 7)) << 3)];
    if (kt + 2 < NK) stg(nb, kt + 2, 1);
    __builtin_amdgcn_s_barrier();
    __builtin_amdgcn_sched_barrier(0);
    __builtin_amdgcn_s_setprio(1);
    #pragma unroll
    for (int mr = 0; mr < 2; mr++)
      #pragma unroll
      for (int nr = 0; nr < 4; nr++)
        #pragma unroll
        for (int ks = 0; ks < 2; ks++)
          acc[mr + 2][nr] = __builtin_amdgcn_mfma_f32_16x16x32_bf16(afr[mr][ks], bfr[nr][ks], acc[mr + 2][nr], 0, 0, 0);
    __builtin_amdgcn_s_setprio(0);
    if (kt < NK - 1) {
      if (kt + 2 < NK)
        asm volatile("s_waitcnt vmcnt(6)" ::: "memory");
      else
        asm volatile("s_waitcnt vmcnt(0)" ::: "memory");
      __builtin_amdgcn_s_barrier();
      __builtin_amdgcn_sched_barrier(0);
    }
  }

  // ---- epilogue ----
  if (QKV && tn >= 1024) {
    #pragma unroll
    for (int mr = 0; mr < 4; mr++) {
      int row0 = (int)tm + wr * 64 + mr * 16 + g * 4;
      int b = row0 >> 11, s0 = row0 & 2047;
      #pragma unroll
      for (int nr = 0; nr < 4; nr++) {
        int colr = (int)(tn - 1024) + wc * 64 + nr * 16 + c;
        int h = colr >> 6, d = colr & 63;
        float bv = bias[1024 + colr];
        u32 w0 = cvtpk(acc[mr][nr][0] + bv, acc[mr][nr][1] + bv);
        u32 w1 = cvtpk(acc[mr][nr][2] + bv, acc[mr][nr][3] + bv);
        u32x2 pp = {w0, w1};
        *(u32x2*)&vTout[((size_t)((b << 3) + h) * 64 + d) * 2048 + s0] = pp;
      }
    }
  } else if (F32OUT) {
    float* Cf = blockIdx.z ? Cf1 : Cf0;
    bool addb = (blockIdx.z == 0);
    #pragma unroll
    for (int nr = 0; nr < 4; nr++) {
      size_t col = tn + wc * 64 + nr * 16 + c;
      float bv = addb ? bias[col] : 0.0f;
      #pragma unroll
      for (int mr = 0; mr < 4; mr++) {
        size_t row0 = tm + wr * 64 + mr * 16 + g * 4;
        #pragma unroll
        for (int r = 0; r < 4; r++) Cf[(row0 + r) * N + col] = acc[mr][nr][r] + bv;
      }
    }
  } else {
    #pragma unroll
    for (int nr = 0; nr < 4; nr++) {
      size_t col = tn + wc * 64 + nr * 16 + c;
      float bv = bias[col];
      #pragma unroll
      for (int mr = 0; mr < 4; mr++) {
        size_t row0 = tm + wr * 64 + mr * 16 + g * 4;
        #pragma unroll
        for (int r = 0; r < 4; r++) {
          float v = acc[mr][nr][r] + bv;
          if (RELU) v = fmaxf(v, 0.0f);
          Cb[(row0 + r) * N + col] = f2bf(v);
        }
      }
    }
  }
}

// ---------------- bf16 MFMA GEMM (small-N path, O-projection) ----------------
template <int BN, bool RELU, bool WF32, bool WBF16>
__global__ __launch_bounds__(256) void k_gemm(const u16* __restrict__ A, const u16* __restrict__ Bt,
                                              const float* __restrict__ bias,
                                              float* __restrict__ Cf, u16* __restrict__ Cb,
                                              int N, int K) {
  constexpr int NACC = BN / 32;
  __shared__ u16 lA[128 * 64];
  __shared__ u16 lB[BN * 64];
  int t = threadIdx.x;
  int lane = t & 63;
  int w = t >> 6;
  int wm = w >> 1, wn = w & 1;
  int g = lane >> 4, c = lane & 15;
  int nwg = gridDim.x * gridDim.y;
  int fid = blockIdx.y * gridDim.x + blockIdx.x;
  int wid = (fid & 7) * (nwg >> 3) + (fid >> 3);
  int bx = wid / gridDim.y;
  int by = wid % gridDim.y;
  size_t tm = (size_t)bx * 128;
  size_t tn = (size_t)by * BN;

  f32x4 acc[4][NACC];
  #pragma unroll
  for (int i = 0; i < 4; i++)
    #pragma unroll
    for (int j = 0; j < NACC; j++) acc[i][j] = (f32x4){0.f, 0.f, 0.f, 0.f};

  for (int k0 = 0; k0 < K; k0 += 64) {
    __syncthreads();
    #pragma unroll
    for (int i = 0; i < 4; i++) {
      int ch = t + i * 256;
      int row = ch >> 3;
      int koff = ((ch ^ row) & 7) << 3;
      gload16(A + (tm + row) * K + k0 + koff, lA + ch * 8);
    }
    #pragma unroll
    for (int i = 0; i < BN / 32; i++) {
      int ch = t + i * 256;
      int row = ch >> 3;
      int koff = ((ch ^ row) & 7) << 3;
      gload16(Bt + (tn + row) * K + k0 + koff, lB + ch * 8);
    }
    __syncthreads();
    #pragma unroll
    for (int kh = 0; kh < 2; kh++) {
      int sl = ((g + 4 * kh) ^ (c & 7)) << 3;
      s16x8 af[4], bf[NACC];
      #pragma unroll
      for (int i = 0; i < 4; i++)
        af[i] = *(const s16x8*)&lA[(wm * 64 + i * 16 + c) * 64 + sl];
      #pragma unroll
      for (int j = 0; j < NACC; j++)
        bf[j] = *(const s16x8*)&lB[(wn * (BN / 2) + j * 16 + c) * 64 + sl];
      #pragma unroll
      for (int i = 0; i < 4; i++)
        #pragma unroll
        for (int j = 0; j < NACC; j++)
          acc[i][j] = __builtin_amdgcn_mfma_f32_16x16x32_bf16(af[i], bf[j], acc[i][j], 0, 0, 0);
    }
  }
  #pragma unroll
  for (int j = 0; j < NACC; j++) {
    size_t col = tn + wn * (BN / 2) + j * 16 + c;
    float bv = bias[col];
    #pragma unroll
    for (int i = 0; i < 4; i++) {
      size_t row0 = tm + wm * 64 + i * 16 + g * 4;
      #pragma unroll
      for (int r = 0; r < 4; r++) {
        float v = acc[i][j][r] + bv;
        if (RELU) v = fmaxf(v, 0.0f);
        if (WF32) Cf[(row0 + r) * N + col] = v;
        if (WBF16) Cb[(row0 + r) * N + col] = f2bf(v);
      }
    }
  }
}

// ---------------- flash attention: 8 waves = 4 q-groups x 2 key-halves, dbuf pipeline ----
// (Round-9-proven structure: vmcnt(0)+barrier per step.) XCD-swizzled 1D grid: each XCD
// owns 4 consecutive bh -> its 2MB K/V slab is L2-resident.
// No online max: P = exp2(s) directly (s bounded); in-block merge of key-halves (l only).
union F16U {
  f32x16 v;
  f32x2 p[8];
};

__global__ __launch_bounds__(512, 4) void k_attn(const u16* __restrict__ qkv,
                                                 const u16* __restrict__ vT,
                                                 u16* __restrict__ ctx) {
  __shared__ u16 lds[8][4096];  // [(stream*2+buf)*2+kv][4096]; 64 KB
  int t = threadIdx.x;
  int w = t >> 6, lane = t & 63;
  int qg = w >> 1, kh = w & 1;
  int ql = lane & 31, hi = lane >> 5;
  int bid = blockIdx.x;
  int wid = (bid & 7) * 64 + (bid >> 3);  // XCD swizzle over 512 blocks
  int bx = wid & 15;
  int bh = wid >> 4;
  int b = bh >> 3, h = bh & 7;
  int q0 = bx * 128 + qg * 32;
  int r7 = ql & 7;

  int sh = t >> 8;
  int th = t & 255;
  const u16* kbaseg = qkv + (size_t)(b * 2048 + sh * 1024) * 1536 + 512 + h * 64;
  const u16* vbaseg = vT + (size_t)(bh * 64) * 2048 + sh * 1024;

  auto stage = [&](int buf, int step) {
    int t0 = step * 64;
    #pragma unroll
    for (int i = 0; i < 2; i++) {
      int ch = th + i * 256;
      int row = ch >> 3;
      int off = ((ch ^ row) & 7) << 3;
      gload16(kbaseg + (size_t)(t0 + row) * 1536 + off, &lds[(sh * 2 + buf) * 2][ch * 8]);
      gload16(vbaseg + (size_t)row * 2048 + t0 + off, &lds[(sh * 2 + buf) * 2 + 1][ch * 8]);
    }
  };

  const u16* qbase = qkv + (size_t)(b * 2048 + q0 + ql) * 1536 + h * 64 + hi * 8;
  s16x8 qf[4];
  #pragma unroll
  for (int ks = 0; ks < 4; ks++) qf[ks] = *(const s16x8*)(qbase + ks * 16);

  float l = 0.f;
  F16U O0, O1;
  #pragma unroll
  for (int i = 0; i < 16; i++) { O0.v[i] = 0.f; O1.v[i] = 0.f; }

  stage(0, 0);

  for (int step = 0; step < 16; ++step) {
    int buf = step & 1;
    asm volatile("s_waitcnt vmcnt(0)" ::: "memory");
    __builtin_amdgcn_s_barrier();
    __builtin_amdgcn_sched_barrier(0);
    if (step < 15) stage(buf ^ 1, step + 1);

    const u16* lK = lds[(kh * 2 + buf) * 2];
    const u16* lV = lds[(kh * 2 + buf) * 2 + 1];

    F16U S0, S1;
    #pragma unroll
    for (int i = 0; i < 16; i++) { S0.v[i] = 0.f; S1.v[i] = 0.f; }
    #pragma unroll
    for (int ks = 0; ks < 4; ks++) {
      int so = ((ks * 2 + hi) ^ r7) << 3;
      s16x8 kf0 = *(const s16x8*)&lK[ql * 64 + so];
      s16x8 kf1 = *(const s16x8*)&lK[(32 + ql) * 64 + so];
      S0.v = __builtin_amdgcn_mfma_f32_32x32x16_bf16(kf0, qf[ks], S0.v, 0, 0, 0);
      S1.v = __builtin_amdgcn_mfma_f32_32x32x16_bf16(kf1, qf[ks], S1.v, 0, 0, 0);
    }

    // P = exp2(s), no max subtraction (softmax shift-invariant; s bounded)
    #pragma unroll
    for (int i = 0; i < 16; i++) {
      S0.v[i] = __builtin_amdgcn_exp2f(S0.v[i]);
      S1.v[i] = __builtin_amdgcn_exp2f(S1.v[i]);
    }
    f32x2 c0 = pk_add(S0.p[0], S0.p[1]);
    f32x2 c1 = pk_add(S0.p[2], S0.p[3]);
    f32x2 c2 = pk_add(S0.p[4], S0.p[5]);
    f32x2 c3 = pk_add(S0.p[6], S0.p[7]);
    f32x2 d0 = pk_add(S1.p[0], S1.p[1]);
    f32x2 d1 = pk_add(S1.p[2], S1.p[3]);
    f32x2 d2 = pk_add(S1.p[4], S1.p[5]);
    f32x2 d3 = pk_add(S1.p[6], S1.p[7]);
    c0 = pk_add(c0, c1);
    c2 = pk_add(c2, c3);
    d0 = pk_add(d0, d1);
    d2 = pk_add(d2, d3);
    c0 = pk_add(c0, c2);
    d0 = pk_add(d0, d2);
    c0 = pk_add(c0, d0);
    float pssum = c0[0] + c0[1];
    pssum += __shfl_xor(pssum, 32, 64);
    l += pssum;

    auto pv = [&](const f32x16& sv, int kb) {
      u32 a0w = cvtpk(sv[0], sv[1]), a1w = cvtpk(sv[2], sv[3]);
      u32 a2w = cvtpk(sv[4], sv[5]), a3w = cvtpk(sv[6], sv[7]);
      u32 b0w = cvtpk(sv[8], sv[9]), b1w = cvtpk(sv[10], sv[11]);
      u32 b2w = cvtpk(sv[12], sv[13]), b3w = cvtpk(sv[14], sv[15]);
      asm("v_permlane32_swap_b32 %0, %1" : "+v"(a0w), "+v"(a2w));
      asm("v_permlane32_swap_b32 %0, %1" : "+v"(a1w), "+v"(a3w));
      asm("v_permlane32_swap_b32 %0, %1" : "+v"(b0w), "+v"(b2w));
      asm("v_permlane32_swap_b32 %0, %1" : "+v"(b1w), "+v"(b3w));
      u32x4 w0v = {a0w, a1w, a2w, a3w};
      u32x4 w1v = {b0w, b1w, b2w, b3w};
      s16x8 pf0 = __builtin_bit_cast(s16x8, w0v);
      s16x8 pf1 = __builtin_bit_cast(s16x8, w1v);
      int base0 = ((kb * 4 + hi) ^ r7) << 3;
      int base1 = ((kb * 4 + 2 + hi) ^ r7) << 3;
      s16x8 vf00 = *(const s16x8*)&lV[ql * 64 + base0];
      s16x8 vf01 = *(const s16x8*)&lV[ql * 64 + base1];
      s16x8 vf10 = *(const s16x8*)&lV[(32 + ql) * 64 + base0];
      s16x8 vf11 = *(const s16x8*)&lV[(32 + ql) * 64 + base1];
      O0.v = __builtin_amdgcn_mfma_f32_32x32x16_bf16(vf00, pf0, O0.v, 0, 0, 0);
      O0.v = __builtin_amdgcn_mfma_f32_32x32x16_bf16(vf01, pf1, O0.v, 0, 0, 0);
      O1.v = __builtin_amdgcn_mfma_f32_32x32x16_bf16(vf10, pf0, O1.v, 0, 0, 0);
      O1.v = __builtin_amdgcn_mfma_f32_32x32x16_bf16(vf11, pf1, O1.v, 0, 0, 0);
    };
    pv(S0.v, 0);
    pv(S1.v, 1);
  }

  // ---- in-block merge of the two key-halves (l only) ----
  asm volatile("s_waitcnt lgkmcnt(0)" ::: "memory");
  __builtin_amdgcn_s_barrier();
  float* mrg = (float*)&lds[0][0];  // [qg*64+lane][34] floats
  float* p = mrg + (size_t)(qg * 64 + lane) * 34;
  if (kh == 1) {
    p[0] = l;
    #pragma unroll
    for (int i = 0; i < 16; i++) {
      p[1 + i] = O0.v[i];
      p[17 + i] = O1.v[i];
    }
  }
  asm volatile("s_waitcnt lgkmcnt(0)" ::: "memory");
  __builtin_amdgcn_s_barrier();
  if (kh == 0) {
    float inv = 1.0f / (l + p[0]);
    size_t obase = (size_t)(b * 2048 + q0 + ql) * 512 + h * 64;
    #pragma unroll
    for (int k = 0; k < 4; k++) {
      float v0 = (O0.v[4 * k] + p[1 + 4 * k]) * inv;
      float v1 = (O0.v[4 * k + 1] + p[1 + 4 * k + 1]) * inv;
      float v2 = (O0.v[4 * k + 2] + p[1 + 4 * k + 2]) * inv;
      float v3 = (O0.v[4 * k + 3] + p[1 + 4 * k + 3]) * inv;
      u32x2 p0 = {cvtpk(v0, v1), cvtpk(v2, v3)};
      *(u32x2*)&ctx[obase + 8 * k + 4 * hi] = p0;
      float u0 = (O1.v[4 * k] + p[17 + 4 * k]) * inv;
      float u1 = (O1.v[4 * k + 1] + p[17 + 4 * k + 1]) * inv;
      float u2 = (O1.v[4 * k + 2] + p[17 + 4 * k + 2]) * inv;
      float u3 = (O1.v[4 * k + 3] + p[17 + 4 * k + 3]) * inv;
      u32x2 p1 = {cvtpk(u0, u1), cvtpk(u2, u3)};
      *(u32x2*)&ctx[obase + 32 + 8 * k + 4 * hi] = p1;
    }
  }
}

// ---------------- residual add + LayerNorm (D=512), optional bf16 copy ----------------
template <bool WB>
__global__ __launch_bounds__(256) void k_addln(const float* __restrict__ A, const float* __restrict__ Bv,
                                               const float* __restrict__ G, const float* __restrict__ Bb,
                                               float* __restrict__ Of, u16* __restrict__ Ob) {
  int row = blockIdx.x;
  int t = threadIdx.x;
  size_t base = (size_t)row * 512 + 2 * t;
  f32x2 av = *(const f32x2*)&A[base];
  f32x2 bv = *(const f32x2*)&Bv[base];
  float x0 = av[0] + bv[0];
  float x1 = av[1] + bv[1];
  float s = x0 + x1;
  #pragma unroll
  for (int d = 1; d < 64; d <<= 1) s += __shfl_xor(s, d, 64);
  __shared__ float red[8];
  int w = t >> 6, lane = t & 63;
  if (lane == 0) red[w] = s;
  __syncthreads();
  float mu = (red[0] + red[1] + red[2] + red[3]) * (1.0f / 512.0f);
  float d0 = x0 - mu, d1 = x1 - mu;
  float vs = d0 * d0 + d1 * d1;
  #pragma unroll
  for (int d = 1; d < 64; d <<= 1) vs += __shfl_xor(vs, d, 64);
  if (lane == 0) red[4 + w] = vs;
  __syncthreads();
  float var = (red[4] + red[5] + red[6] + red[7]) * (1.0f / 512.0f);
  float rs = rsqrtf(var + 1e-5f);
  f32x2 gg = *(const f32x2*)&G[2 * t];
  f32x2 bb = *(const f32x2*)&Bb[2 * t];
  float o0 = d0 * rs * gg[0] + bb[0];
  float o1 = d1 * rs * gg[1] + bb[1];
  *(f32x2*)&Of[base] = (f32x2){o0, o1};
  if (WB) *(u32*)&Ob[base] = cvtpk(o0, o1);
}

// ---------------- 3-way residual add + LayerNorm (final, f32 out only) ----------------
__global__ __launch_bounds__(256) void k_addln3(const float* __restrict__ A, const float* __restrict__ B1,
                                                const float* __restrict__ B2,
                                                const float* __restrict__ G, const float* __restrict__ Bb,
                                                float* __restrict__ Of) {
  int row = blockIdx.x;
  int t = threadIdx.x;
  size_t base = (size_t)row * 512 + 2 * t;
  f32x2 av = *(const f32x2*)&A[base];
  f32x2 b1v = *(const f32x2*)&B1[base];
  f32x2 b2v = *(const f32x2*)&B2[base];
  float x0 = av[0] + b1v[0] + b2v[0];
  float x1 = av[1] + b1v[1] + b2v[1];
  float s = x0 + x1;
  #pragma unroll
  for (int d = 1; d < 64; d <<= 1) s += __shfl_xor(s, d, 64);
  __shared__ float red[8];
  int w = t >> 6, lane = t & 63;
  if (lane == 0) red[w] = s;
  __syncthreads();
  float mu = (red[0] + red[1] + red[2] + red[3]) * (1.0f / 512.0f);
  float d0 = x0 - mu, d1 = x1 - mu;
  float vs = d0 * d0 + d1 * d1;
  #pragma unroll
  for (int d = 1; d < 64; d <<= 1) vs += __shfl_xor(vs, d, 64);
  if (lane == 0) red[4 + w] = vs;
  __syncthreads();
  float var = (red[4] + red[5] + red[6] + red[7]) * (1.0f / 512.0f);
  float rs = rsqrtf(var + 1e-5f);
  f32x2 gg = *(const f32x2*)&G[2 * t];
  f32x2 bb = *(const f32x2*)&Bb[2 * t];
  float o0 = d0 * rs * gg[0] + bb[0];
  float o1 = d1 * rs * gg[1] + bb[1];
  *(f32x2*)&Of[base] = (f32x2){o0, o1};
}

// ---------------- launch ----------------
extern "C" void kernel_launch(void* const* d_in, const int* in_sizes, int n_in,
                              void* d_out, int out_size, void* d_ws, size_t ws_size,
                              hipStream_t stream) {
  const float* x = (const float*)d_in[0];
  const float* Wq = (const float*)d_in[1];
  const float* bq = (const float*)d_in[2];
  const float* Wk = (const float*)d_in[3];
  const float* bk = (const float*)d_in[4];
  const float* Wv = (const float*)d_in[5];
  const float* bv = (const float*)d_in[6];
  const float* Wo = (const float*)d_in[7];
  const float* bo = (const float*)d_in[8];
  const float* g1 = (const float*)d_in[9];
  const float* b1 = (const float*)d_in[10];
  const float* Wff1 = (const float*)d_in[11];
  const float* bff1 = (const float*)d_in[12];
  const float* Wff2 = (const float*)d_in[13];
  const float* bff2 = (const float*)d_in[14];
  const float* g2 = (const float*)d_in[15];
  const float* b2 = (const float*)d_in[16];

  char* ws = (char*)d_ws;
  float* xpe_f = (float*)(ws + 0);            // 16MB (dead after addln<true> -> reused as ao2)
  float* ao2 = (float*)(ws + 0);              // 16MB FF2 partial z=1
  u16* xpe_b = (u16*)(ws + 16 * MB);          // 8MB
  u16* qkv = (u16*)(ws + 24 * MB);            // 24MB  [8192][1536] (V cols unused)
  u16* vT = (u16*)(ws + 48 * MB);             // 8MB   [32][64][2048]
  u16* ctx = (u16*)(ws + 56 * MB);            // 8MB   [8192][512]
  float* ao = (float*)(ws + 64 * MB);         // 16MB  attn_out / FF2 partial z=0
  float* hf = (float*)(ws + 80 * MB);         // 16MB
  u16* hb = (u16*)(ws + 96 * MB);             // 8MB
  u16* ff1 = (u16*)(ws + 24 * MB);            // 32MB, aliases qkv+vT (dead by then)
  u16* WqkvT = (u16*)(ws + 104 * MB);         // 1.5MB [1536][512]
  u16* WoT = (u16*)(ws + 106 * MB);           // 0.5MB
  u16* Wff1T = (u16*)(ws + 107 * MB);         // 2MB [2048][512]
  u16* Wff2T = (u16*)(ws + 109 * MB);         // 2MB [512][2048]
  float* bqkv = (float*)(ws + 111 * MB);      // 6KB
  (void)in_sizes; (void)n_in; (void)out_size; (void)ws_size;

  k_prep<<<11270, 256, 0, stream>>>(x, xpe_f, xpe_b, Wq, Wk, Wv, Wo, Wff1, Wff2,
                                    bq, bk, bv, WqkvT, WoT, Wff1T, Wff2T, bqkv);

  // fused QKV projection (V written transposed straight into vT)
  k_gemm3<8, false, true, false><<<dim3(32, 12), 512, 0, stream>>>(xpe_b, WqkvT, bqkv, qkv, vT,
                                                                   nullptr, nullptr, 1536, 512);
  k_attn<<<512, 512, 0, stream>>>(qkv, vT, ctx);
  // O projection
  k_gemm<64, false, true, false><<<dim3(64, 8), 256, 0, stream>>>(ctx, WoT, bo, ao, nullptr, 512, 512);
  k_addln<true><<<8192, 256, 0, stream>>>(xpe_f, ao, g1, b1, hf, hb);
  // FFN
  k_gemm3<8, true, false, false><<<dim3(32, 16), 512, 0, stream>>>(hb, Wff1T, bff1, ff1, nullptr,
                                                                   nullptr, nullptr, 2048, 512);
  // FF2 split-K x2, pipelined, f32 partials (z=0 -> ao with bias, z=1 -> ao2)
  k_gemm3<16, false, false, true><<<dim3(32, 4, 2), 512, 0, stream>>>(ff1, Wff2T, bff2, nullptr, nullptr,
                                                                      ao, ao2, 512, 2048);
  k_addln3<<<8192, 256, 0, stream>>>(hf, ao, ao2, g2, b2, (float*)d_out);
}